// Round 4
// baseline (295.679 us; speedup 1.0000x reference)
//
#include <hip/hip_runtime.h>

// WARP loss: B=4096 rows, Y=10000 labels, T=128 negative-candidate trials.
// input [B,Y] f32, target [B,Y] f32 (one-hot), neg_candidates [B,T] i32.
// out[0] = sum over rows of log((Y-1)/num_trials) * (1 - s_pos + s_neg),
// num_trials = 1 + first t with 1 + s_neg_t - s_pos >= 0 (0 contribution if none).
//
// One wave per row. Depth-2 software-pipelined early-exit scan:
//   chunks of 4 wave-groups (4 KB); chunk k+1 in flight while checking k;
//   chunk k+2 issued BEFORE checking k+1 -> 8-12 KB in flight per wave,
//   counted vmcnt waits (named registers, all static indices).
// neg indices + candidate gathers issued around the scan prologue so they
// complete underneath it. Dependent tail: one s_pos gather, ballots, shfl.
// Per-block partials in d_ws; 1-block reduce writes out[0] (overwrites poison).

constexpr int Yc   = 10000;
constexpr int Tc   = 128;
constexpr int R4   = 2500;   // uint4 per row (40 KB, 16B-aligned per row)
constexpr int NCHK = 10;     // chunks of 4 groups (4 KB) per row

__global__ __launch_bounds__(256) void warp_fused_kernel(
        const float* __restrict__ input,
        const float* __restrict__ target,
        const int*   __restrict__ neg,
        float* __restrict__ partial,
        int B) {
    const int wave = threadIdx.x >> 6;
    const int lane = threadIdx.x & 63;
    const int row  = blockIdx.x * 4 + wave;

    __shared__ float sacc[4];
    float contrib = 0.0f;

    if (row < B) {
        const int*   nrow = neg + row * Tc;
        const float* irow = input + (size_t)row * Yc;
        const uint4* trow = reinterpret_cast<const uint4*>(target + (size_t)row * Yc);

        // group g, this lane's uint4 (clamped; harmless re-read of last uint4)
        auto LDG = [&](int g) -> uint4 {
            int idx = g * 64 + lane;
            return trow[idx < R4 ? idx : R4 - 1];
        };
        // min one-hot element index within a 4-group chunk, or -1
        auto CHECK = [&](int gb, const uint4& v0, const uint4& v1,
                                 const uint4& v2, const uint4& v3) -> int {
            const unsigned nz0 = v0.x | v0.y | v0.z | v0.w;
            const unsigned nz1 = v1.x | v1.y | v1.z | v1.w;
            const unsigned nz2 = v2.x | v2.y | v2.z | v2.w;
            const unsigned nz3 = v3.x | v3.y | v3.z | v3.w;
            if (!__any((nz0 | nz1 | nz2 | nz3) != 0)) return -1;
            int mine = 0x7fffffff;
            auto CND = [&](int g, const uint4& v, unsigned nz) {
                if (nz) {
                    int idx = g * 64 + lane;
                    if (idx >= R4) idx = R4 - 1;
                    int sub = v.x ? 0 : (v.y ? 1 : (v.z ? 2 : 3));
                    mine = min(mine, 4 * idx + sub);
                }
            };
            CND(gb, v0, nz0); CND(gb + 1, v1, nz1);
            CND(gb + 2, v2, nz2); CND(gb + 3, v3, nz3);
            #pragma unroll
            for (int off = 32; off; off >>= 1)
                mine = min(mine, __shfl_xor(mine, off));
            return mine;
        };

        // ---- prologue: neg (coalesced, oldest), chunks 0+1, then gathers ----
        const int c0 = nrow[lane];
        const int c1 = nrow[lane + 64];
        uint4 A0 = LDG(0), A1 = LDG(1), A2 = LDG(2), A3 = LDG(3);
        uint4 B0 = LDG(4), B1 = LDG(5), B2 = LDG(6), B3 = LDG(7);
        const float s0 = irow[c0];   // waits only on neg; A/B stay in flight
        const float s1 = irow[c1];

        // ---- depth-2 pipelined scan ----
        int posIdx = -1;
        for (int ch = 0; ch < NCHK; ch += 2) {
            posIdx = CHECK(ch * 4, A0, A1, A2, A3);          // waits A only
            if (posIdx >= 0) break;
            if (ch + 2 < NCHK) {                              // refill A early
                const int gb = (ch + 2) * 4;
                A0 = LDG(gb); A1 = LDG(gb + 1); A2 = LDG(gb + 2); A3 = LDG(gb + 3);
            }
            posIdx = CHECK((ch + 1) * 4, B0, B1, B2, B3);     // waits B only
            if (posIdx >= 0) break;
            if (ch + 3 < NCHK) {                              // refill B early
                const int gb = (ch + 3) * 4;
                B0 = LDG(gb); B1 = LDG(gb + 1); B2 = LDG(gb + 2); B3 = LDG(gb + 3);
            }
        }

        // ---- dependent tail ----
        float s_pos = 0.0f;
        if (posIdx >= 0) s_pos = irow[posIdx];

        const unsigned long long b0m = __ballot(1.0f + s0 - s_pos >= 0.0f);
        const unsigned long long b1m = __ballot(1.0f + s1 - s_pos >= 0.0f);
        int   first = -1;
        float s_neg = 0.0f;
        if (b0m) {
            first = __ffsll(b0m) - 1;
            s_neg = __shfl(s0, first);
        } else if (b1m) {
            first = 64 + __ffsll(b1m) - 1;
            s_neg = __shfl(s1, first - 64);
        }
        if (posIdx >= 0 && first >= 0) {
            const int   nt = first + 1;
            const float L  = logf((float)((Yc - 1) / nt));   // floor-div then log
            contrib = L * (1.0f - s_pos + s_neg);
        }
    }

    if (lane == 0) sacc[wave] = contrib;   // contrib is wave-uniform
    __syncthreads();
    if (threadIdx.x == 0)
        partial[blockIdx.x] = sacc[0] + sacc[1] + sacc[2] + sacc[3];
}

__global__ __launch_bounds__(256) void reduce_partials(
        const float* __restrict__ partial,
        float* __restrict__ out, int n) {
    float s = 0.0f;
    for (int i = threadIdx.x; i < n; i += 256) s += partial[i];
    #pragma unroll
    for (int off = 32; off; off >>= 1) s += __shfl_down(s, off);
    __shared__ float ws[4];
    if ((threadIdx.x & 63) == 0) ws[threadIdx.x >> 6] = s;
    __syncthreads();
    if (threadIdx.x == 0) out[0] = ws[0] + ws[1] + ws[2] + ws[3];
}

extern "C" void kernel_launch(void* const* d_in, const int* in_sizes, int n_in,
                              void* d_out, int out_size, void* d_ws, size_t ws_size,
                              hipStream_t stream) {
    const float* input  = (const float*)d_in[0];
    const float* target = (const float*)d_in[1];
    const int*   neg    = (const int*)d_in[2];
    float* out     = (float*)d_out;
    float* partial = (float*)d_ws;             // nblk floats

    const int B    = in_sizes[2] / Tc;         // 4096
    const int nblk = (B + 3) / 4;              // 1024 blocks, 1 wave per row

    warp_fused_kernel<<<nblk, 256, 0, stream>>>(input, target, neg, partial, B);
    reduce_partials<<<1, 256, 0, stream>>>(partial, out, nblk);
}

// Round 5
// 282.127 us; speedup vs baseline: 1.0480x; 1.0480x over previous
//
#include <hip/hip_runtime.h>

// WARP loss: B=4096 rows, Y=10000 labels, T=128 negative-candidate trials.
// input [B,Y] f32, target [B,Y] f32 (one-hot), neg_candidates [B,T] i32.
// out[0] = sum over rows of log((Y-1)/num_trials) * (1 - s_pos + s_neg),
// num_trials = 1 + first t with 1 + s_neg_t - s_pos >= 0 (0 contribution if none).
//
// Byte-minimized one-wave-per-row design (time ~ bytes / effective BW):
//   - target scan: 2 KB chunks, early exit, refill AFTER check (overshoot
//     <= 4 KB/row); expected target read ~ 24 KB/row (~98 MB total)
//   - candidates: progressive widening. Stage A = first 16 candidates
//     (prefetched under the scan, ~16 cache lines). Accept prob/trial ~0.76
//     -> fallback to trials 16..79 / 80..127 needed for only ~1-2% of rows.
//     Cuts gather traffic 67 MB -> ~9 MB. First-accept semantics preserved:
//     deeper stages run only when ALL earlier trials were rejected.
//   - per-block partials in d_ws; 1-block reduce writes out[0] (overwrites
//     harness poison; no memset, no global atomics, no init needed).

constexpr int Yc  = 10000;
constexpr int Tc  = 128;
constexpr int R4  = 2500;   // uint4 per row (40 KB, 16B-aligned per row)
constexpr int NCH = 20;     // 2-group (2 KB) chunks per row

__global__ __launch_bounds__(256) void warp_fused_kernel(
        const float* __restrict__ input,
        const float* __restrict__ target,
        const int*   __restrict__ neg,
        float* __restrict__ partial,
        int B) {
    const int wave = threadIdx.x >> 6;
    const int lane = threadIdx.x & 63;
    const int row  = blockIdx.x * 4 + wave;

    __shared__ float sacc[4];
    float contrib = 0.0f;

    if (row < B) {
        const int*   nrow = neg + row * Tc;
        const float* irow = input + (size_t)row * Yc;
        const uint4* trow = reinterpret_cast<const uint4*>(target + (size_t)row * Yc);

        auto LDG = [&](int g) -> uint4 {                 // group g, lane's uint4
            int idx = g * 64 + lane;
            return trow[idx < R4 ? idx : R4 - 1];        // clamp: harmless re-read
        };
        // min one-hot element index within a 2-group chunk, or -1
        auto CHK2 = [&](int gb, const uint4& v0, const uint4& v1) -> int {
            const unsigned nz0 = v0.x | v0.y | v0.z | v0.w;
            const unsigned nz1 = v1.x | v1.y | v1.z | v1.w;
            if (!__any((nz0 | nz1) != 0)) return -1;
            int mine = 0x7fffffff;
            if (nz0) { int idx = gb * 64 + lane; if (idx >= R4) idx = R4 - 1;
                       int sub = v0.x ? 0 : (v0.y ? 1 : (v0.z ? 2 : 3));
                       mine = 4 * idx + sub; }
            if (nz1) { int idx = (gb + 1) * 64 + lane; if (idx >= R4) idx = R4 - 1;
                       int sub = v1.x ? 0 : (v1.y ? 1 : (v1.z ? 2 : 3));
                       mine = min(mine, 4 * idx + sub); }
            #pragma unroll
            for (int off = 32; off; off >>= 1)
                mine = min(mine, __shfl_xor(mine, off));
            return mine;
        };

        // ---- prologue: stage-A neg (1 line) + gathers (<=16 lines) fly
        //      under the scan; chunks 0,1 issued up front ----
        const int cA = nrow[lane & 15];                  // candidates 0..15, x4 dup
        uint4 A0 = LDG(0), A1 = LDG(1);
        uint4 B0 = LDG(2), B1 = LDG(3);
        const float sA = irow[cA];                       // waits only on cA

        // ---- early-exit scan, ping-pong chunks, refill after check ----
        int posIdx = -1;
        for (int ch = 0; ch < NCH; ch += 2) {
            posIdx = CHK2(ch * 2, A0, A1);               // chunk ch
            if (posIdx >= 0) break;
            if (ch + 2 < NCH) { A0 = LDG((ch + 2) * 2); A1 = LDG((ch + 2) * 2 + 1); }
            posIdx = CHK2((ch + 1) * 2, B0, B1);         // chunk ch+1
            if (posIdx >= 0) break;
            if (ch + 3 < NCH) { B0 = LDG((ch + 3) * 2); B1 = LDG((ch + 3) * 2 + 1); }
        }

        const float s_pos = (posIdx >= 0) ? irow[posIdx] : 0.0f;  // 1 line, bcast

        // ---- progressive first-accept ----
        int   first = -1;
        float s_neg = 0.0f;
        const unsigned long long bA =
            __ballot(1.0f + sA - s_pos >= 0.0f) & 0xFFFFull;     // trials 0..15
        if (bA) {
            first = __ffsll(bA) - 1;
            s_neg = __shfl(sA, first);
        } else {
            const int   cB = nrow[16 + lane];                    // trials 16..79
            const float sB = irow[cB];
            const unsigned long long bB = __ballot(1.0f + sB - s_pos >= 0.0f);
            if (bB) {
                const int f = __ffsll(bB) - 1;
                first = 16 + f;
                s_neg = __shfl(sB, f);
            } else {
                const int   iC = 80 + lane;                      // trials 80..127
                const int   cC = nrow[iC < Tc ? iC : Tc - 1];
                const float sC = irow[cC];
                const unsigned long long bC =
                    __ballot(1.0f + sC - s_pos >= 0.0f) & ((1ull << 48) - 1);
                if (bC) {
                    const int f = __ffsll(bC) - 1;
                    first = 80 + f;
                    s_neg = __shfl(sC, f);
                }
            }
        }

        if (posIdx >= 0 && first >= 0) {
            const int   nt = first + 1;
            const float L  = logf((float)((Yc - 1) / nt));       // floor-div, log
            contrib = L * (1.0f - s_pos + s_neg);
        }
    }

    if (lane == 0) sacc[wave] = contrib;   // contrib is wave-uniform
    __syncthreads();
    if (threadIdx.x == 0)
        partial[blockIdx.x] = sacc[0] + sacc[1] + sacc[2] + sacc[3];
}

__global__ __launch_bounds__(256) void reduce_partials(
        const float* __restrict__ partial,
        float* __restrict__ out, int n) {
    float s = 0.0f;
    for (int i = threadIdx.x; i < n; i += 256) s += partial[i];
    #pragma unroll
    for (int off = 32; off; off >>= 1) s += __shfl_down(s, off);
    __shared__ float ws[4];
    if ((threadIdx.x & 63) == 0) ws[threadIdx.x >> 6] = s;
    __syncthreads();
    if (threadIdx.x == 0) out[0] = ws[0] + ws[1] + ws[2] + ws[3];
}

extern "C" void kernel_launch(void* const* d_in, const int* in_sizes, int n_in,
                              void* d_out, int out_size, void* d_ws, size_t ws_size,
                              hipStream_t stream) {
    const float* input  = (const float*)d_in[0];
    const float* target = (const float*)d_in[1];
    const int*   neg    = (const int*)d_in[2];
    float* out     = (float*)d_out;
    float* partial = (float*)d_ws;             // nblk floats

    const int B    = in_sizes[2] / Tc;         // 4096
    const int nblk = (B + 3) / 4;              // 1024 blocks, 1 wave per row

    warp_fused_kernel<<<nblk, 256, 0, stream>>>(input, target, neg, partial, B);
    reduce_partials<<<1, 256, 0, stream>>>(partial, out, nblk);
}